// Round 12
// baseline (372.735 us; speedup 1.0000x reference)
//
#include <hip/hip_runtime.h>
#include <hip/hip_cooperative_groups.h>

namespace cg = cooperative_groups;

typedef __attribute__((ext_vector_type(8))) short bf16x8;
typedef __attribute__((ext_vector_type(4))) float f32x4;

namespace {
constexpr int L = 32, T = 64, D = 8192, H = 16;
constexpr int M = L * T;      // 2048 hutch rows
constexpr int KP = 32;        // k-split in GEMM phase
constexpr int CHUNK = D / KP; // 256

// workspace layout (in floats)
constexpr size_t WS_WH  = 0;                          // wcat_hi: 32*8192 ushort
constexpr size_t WS_WL  = WS_WH + 32 * 8192 / 2;      // wcat_lo: 32*8192 ushort
constexpr size_t WS_PRE = WS_WL + 32 * 8192 / 2;      // [32][8][16] preact partials
constexpr size_t WS_AC  = WS_PRE + 32 * 8 * 16;       // [M][32] fp32 accum (atomicAdd)
}

// split f into bf16 hi (truncated) + bf16 lo s.t. hi+lo ~= f to ~2^-16 rel
__device__ inline void split1(float f, short& h, short& l) {
  unsigned b = __float_as_uint(f);
  h = (short)(b >> 16);
  float lf = f - __uint_as_float(b & 0xFFFF0000u);  // exact remainder
  l = (short)(__float_as_uint(lf) >> 16);
}

__device__ inline void split8(float4 a0, float4 a1, bf16x8& h, bf16x8& l) {
  float f[8] = {a0.x, a0.y, a0.z, a0.w, a1.x, a1.y, a1.z, a1.w};
#pragma unroll
  for (int i = 0; i < 8; ++i) {
    short hh, ll;
    split1(f[i], hh, ll);
    h[i] = hh; l[i] = ll;
  }
}

// Single cooperative kernel, 1024 blocks x 256 threads, 3 phases:
//  A: setup  (wcat split roles, zero-ac, preact partials)
//  B: GEMM   (kp = b&31, rowgroup = b>>5; r5-identical fragment-direct MFMA)
//  C: tail   (f output + trace reduction)
__global__ __launch_bounds__(256, 4) void k_fused(
    const float* __restrict__ u, const float* __restrict__ w,
    const float* __restrict__ W1, const float* __restrict__ b1,
    const float* __restrict__ W2, const float* __restrict__ b2,
    ushort* __restrict__ wh, ushort* __restrict__ wl,
    float* __restrict__ pre, float* __restrict__ ac,
    float* __restrict__ out) {
  cg::grid_group grid = cg::this_grid();
  __shared__ float redA[4][16];
  __shared__ float hl[8][16];
  __shared__ float s[16];
  __shared__ float redC[4];

  const int b = blockIdx.x, tid = threadIdx.x;

  // ================= Phase A: setup =================
  if (b == 0 && tid == 0) out[(size_t)L * D] = 0.f;
  if (b < 32) {
    // W2 transpose + split -> wcat cols 0..15
    int d = b * 256 + tid;
    const float4* src = reinterpret_cast<const float4*>(W2 + (size_t)d * 16);
    float4 q0 = src[0], q1 = src[1], q2 = src[2], q3 = src[3];
    float v[16] = {q0.x, q0.y, q0.z, q0.w, q1.x, q1.y, q1.z, q1.w,
                   q2.x, q2.y, q2.z, q2.w, q3.x, q3.y, q3.z, q3.w};
#pragma unroll
    for (int c = 0; c < 16; ++c) {
      short hh, ll;
      split1(v[c], hh, ll);
      wh[(size_t)c * D + d] = (ushort)hh;
      wl[(size_t)c * D + d] = (ushort)ll;
    }
  } else if (b < 64) {
    // W1 split -> wcat cols 16..31 (131072 floats = 32768 float4s)
    int q = (b - 32) * 256 + tid;  // 0..8191
#pragma unroll
    for (int j = 0; j < 4; ++j) {
      int idx = (q + j * 8192) * 4;
      float4 qv = *reinterpret_cast<const float4*>(W1 + idx);
      short h0, l0, h1, l1, h2, l2, h3, l3;
      split1(qv.x, h0, l0); split1(qv.y, h1, l1);
      split1(qv.z, h2, l2); split1(qv.w, h3, l3);
      ushort4 vh = {(ushort)h0, (ushort)h1, (ushort)h2, (ushort)h3};
      ushort4 vl = {(ushort)l0, (ushort)l1, (ushort)l2, (ushort)l3};
      *reinterpret_cast<ushort4*>(wh + (size_t)16 * D + idx) = vh;
      *reinterpret_cast<ushort4*>(wl + (size_t)16 * D + idx) = vl;
    }
  } else if (b < 80) {
    // zero ac (65536 floats)
    int t = (b - 64) * 256 + tid;
    float4 z = {0.f, 0.f, 0.f, 0.f};
    float4* dst = reinterpret_cast<float4*>(ac);
#pragma unroll
    for (int j = 0; j < 4; ++j) dst[t + j * 4096] = z;
  } else if (b < 336) {
    // preact partials pre[l][kc][h]
    int bb = b - 80;
    int kc = bb & 7, l = bb >> 3;
    int d = kc * 1024 + tid * 4;
    float4 uv = *reinterpret_cast<const float4*>(u + (size_t)l * D + d);
    float acc[16];
#pragma unroll
    for (int h = 0; h < 16; ++h) {
      float4 wv = *reinterpret_cast<const float4*>(W1 + (size_t)h * D + d);
      float t = fmaf(uv.x, wv.x, 0.f);
      t = fmaf(uv.y, wv.y, t);
      t = fmaf(uv.z, wv.z, t);
      acc[h] = fmaf(uv.w, wv.w, t);
    }
#pragma unroll
    for (int h = 0; h < 16; ++h)
      for (int off = 1; off < 64; off <<= 1) acc[h] += __shfl_xor(acc[h], off);
    int lane = tid & 63, wv_ = tid >> 6;
    if (lane == 0) {
#pragma unroll
      for (int h = 0; h < 16; ++h) redA[wv_][h] = acc[h];
    }
    __syncthreads();
    if (tid < 16)
      pre[((size_t)l * 8 + kc) * 16 + tid] =
          redA[0][tid] + redA[1][tid] + redA[2][tid] + redA[3][tid];
  }

  grid.sync();

  // ================= Phase B: trace GEMM (r5-identical) =================
  {
    int wave = tid >> 6, lane = tid & 63;
    int lrow = lane & 15, kg = lane >> 4;
    int kp = b & 31;
    int rt = (b >> 5) * 4 + wave;   // rowtile 0..127
    int m0 = rt * 16;
    int k0 = kp * CHUNK;

    const float*  wrow = w  + (size_t)(m0 + lrow) * D + k0 + kg * 8;
    const ushort* bh0  = wh + (size_t)lrow * D + k0 + kg * 8;
    const ushort* bl0  = wl + (size_t)lrow * D + k0 + kg * 8;
    const ushort* bh1  = bh0 + (size_t)16 * D;
    const ushort* bl1  = bl0 + (size_t)16 * D;

    f32x4 acc0 = {0.f, 0.f, 0.f, 0.f};
    f32x4 acc1 = {0.f, 0.f, 0.f, 0.f};

#pragma unroll
    for (int kk = 0; kk < CHUNK / 32; ++kk) {
      int off = kk * 32;
      float4 a0 = *reinterpret_cast<const float4*>(wrow + off);
      float4 a1 = *reinterpret_cast<const float4*>(wrow + off + 4);
      bf16x8 ah, al;
      split8(a0, a1, ah, al);
      bf16x8 vbh0 = *reinterpret_cast<const bf16x8*>(bh0 + off);
      bf16x8 vbl0 = *reinterpret_cast<const bf16x8*>(bl0 + off);
      bf16x8 vbh1 = *reinterpret_cast<const bf16x8*>(bh1 + off);
      bf16x8 vbl1 = *reinterpret_cast<const bf16x8*>(bl1 + off);
      acc0 = __builtin_amdgcn_mfma_f32_16x16x32_bf16(ah, vbh0, acc0, 0, 0, 0);
      acc0 = __builtin_amdgcn_mfma_f32_16x16x32_bf16(ah, vbl0, acc0, 0, 0, 0);
      acc0 = __builtin_amdgcn_mfma_f32_16x16x32_bf16(al, vbh0, acc0, 0, 0, 0);
      acc1 = __builtin_amdgcn_mfma_f32_16x16x32_bf16(ah, vbh1, acc1, 0, 0, 0);
      acc1 = __builtin_amdgcn_mfma_f32_16x16x32_bf16(ah, vbl1, acc1, 0, 0, 0);
      acc1 = __builtin_amdgcn_mfma_f32_16x16x32_bf16(al, vbh1, acc1, 0, 0, 0);
    }

    // C/D layout: col = lane&15, row = (lane>>4)*4 + reg  [measured m89]
    float* dst = ac + (size_t)(m0 + kg * 4) * 32;
#pragma unroll
    for (int j = 0; j < 4; ++j) {
      atomicAdd(dst + (size_t)j * 32 + lrow,      acc0[j]);
      atomicAdd(dst + (size_t)j * 32 + 16 + lrow, acc1[j]);
    }
  }

  grid.sync();

  // ================= Phase C: tail =================
  if (b < 128) {
    // f[l][d] = b2[d] + sum_h tanh(pre_l_h) * W2[d][h]
    int lg = b >> 5;
    if (tid < 128) {
      int ll = tid >> 4, h = tid & 15, l = lg * 8 + ll;
      float p = b1[h];
#pragma unroll
      for (int kc = 0; kc < 8; ++kc) p += pre[((size_t)l * 8 + kc) * 16 + h];
      hl[ll][h] = tanhf(p);
    }
    __syncthreads();
    int d = (b & 31) * 256 + tid;
    const float4* w2r = reinterpret_cast<const float4*>(W2 + (size_t)d * 16);
    float4 q0 = w2r[0], q1 = w2r[1], q2 = w2r[2], q3 = w2r[3];
    float w2v[16] = {q0.x, q0.y, q0.z, q0.w, q1.x, q1.y, q1.z, q1.w,
                     q2.x, q2.y, q2.z, q2.w, q3.x, q3.y, q3.z, q3.w};
    float bv = b2[d];
#pragma unroll
    for (int ll = 0; ll < 8; ++ll) {
      float fv = bv;
#pragma unroll
      for (int h = 0; h < 16; ++h) fv = fmaf(hl[ll][h], w2v[h], fv);
      out[(size_t)(lg * 8 + ll) * D + d] = fv;
    }
  } else if (b < 384) {
    // trace reduction: 8 rows per block
    int bb = b - 128;           // 0..255
    int l = bb >> 3;
    if (tid < 16) {
      float p = b1[tid];
#pragma unroll
      for (int kc = 0; kc < 8; ++kc) p += pre[((size_t)l * 8 + kc) * 16 + tid];
      float t = tanhf(p);
      s[tid] = 1.f - t * t;
    }
    __syncthreads();
    int c = tid & 31;
    float acc = ac[(size_t)bb * 256 + tid];  // contiguous [8 rows][32]
    float partner = __shfl_xor(acc, 16);
    float t = (c < 16) ? s[c] * acc * partner : 0.f;
#pragma unroll
    for (int off = 1; off < 64; off <<= 1) t += __shfl_xor(t, off);
    int lane = tid & 63, wv_ = tid >> 6;
    if (lane == 0) redC[wv_] = t;
    __syncthreads();
    if (tid == 0)
      atomicAdd(out + (size_t)L * D,
                (redC[0] + redC[1] + redC[2] + redC[3]) * (1.0f / (float)(L * T)));
  }
}

extern "C" void kernel_launch(void* const* d_in, const int* in_sizes, int n_in,
                              void* d_out, int out_size, void* d_ws, size_t ws_size,
                              hipStream_t stream) {
  const float* u  = (const float*)d_in[0];
  const float* w  = (const float*)d_in[1];
  const float* W1 = (const float*)d_in[2];
  const float* b1 = (const float*)d_in[3];
  const float* W2 = (const float*)d_in[4];
  const float* b2 = (const float*)d_in[5];
  float* out = (float*)d_out;
  float* ws  = (float*)d_ws;
  ushort* wcat_h = (ushort*)(ws + WS_WH);
  ushort* wcat_l = (ushort*)(ws + WS_WL);
  float* pre = ws + WS_PRE;
  float* acb = ws + WS_AC;

  void* args[] = {(void*)&u, (void*)&w, (void*)&W1, (void*)&b1, (void*)&W2,
                  (void*)&b2, (void*)&wcat_h, (void*)&wcat_l, (void*)&pre,
                  (void*)&acb, (void*)&out};
  hipLaunchCooperativeKernel((const void*)k_fused, dim3(1024), dim3(256),
                             args, 0, stream);
}

// Round 15
// 127.743 us; speedup vs baseline: 2.9178x; 2.9178x over previous
//
#include <hip/hip_runtime.h>

typedef __attribute__((ext_vector_type(8))) short bf16x8;
typedef __attribute__((ext_vector_type(4))) float f32x4;

namespace {
constexpr int L = 32, T = 64, D = 8192, H = 16;
constexpr int M = L * T;      // 2048 hutch rows
constexpr int KP = 32;        // k-split in trace kernel
constexpr int CHUNK = D / KP; // 256

// workspace layout (in floats); ws_size ~268 MB, we use ~1.3 MB
constexpr size_t WS_WH  = 0;                          // wcat_hi: 32*8192 ushort
constexpr size_t WS_WL  = WS_WH + 32 * 8192 / 2;      // wcat_lo: 32*8192 ushort
constexpr size_t WS_PRE = WS_WL + 32 * 8192 / 2;      // [32][8][16] preact partials
constexpr size_t WS_AC  = WS_PRE + 32 * 8 * 16;       // [M][32] fp32 accum (atomicAdd)
}

// split f into bf16 hi (truncated) + bf16 lo s.t. hi+lo ~= f to ~2^-16 rel
__device__ inline void split1(float f, short& h, short& l) {
  unsigned b = __float_as_uint(f);
  h = (short)(b >> 16);
  float lf = f - __uint_as_float(b & 0xFFFF0000u);  // exact remainder
  l = (short)(__float_as_uint(lf) >> 16);
}

__device__ inline void split8(float4 a0, float4 a1, bf16x8& h, bf16x8& l) {
  float f[8] = {a0.x, a0.y, a0.z, a0.w, a1.x, a1.y, a1.z, a1.w};
#pragma unroll
  for (int i = 0; i < 8; ++i) {
    short hh, ll;
    split1(f[i], hh, ll);
    h[i] = hh; l[i] = ll;
  }
}

// K1 (fused setup, role-split by blockIdx.x):
//   [0,32):   W2 transpose+split -> wcat cols 0..15
//   [32,64):  W1 split -> wcat cols 16..31
//   [64,80):  zero ac accumulator
//   [80,336): preact partials pre[l][kc][h]
__global__ __launch_bounds__(256) void k_setup(
    const float* __restrict__ u, const float* __restrict__ W1,
    const float* __restrict__ W2,
    ushort* __restrict__ wh, ushort* __restrict__ wl,
    float* __restrict__ pre, float* __restrict__ ac,
    float* __restrict__ out) {
  int b = blockIdx.x, tid = threadIdx.x;
  if (b == 0 && tid == 0) out[(size_t)L * D] = 0.f;
  if (b < 32) {
    int d = b * 256 + tid;
    const float4* src = reinterpret_cast<const float4*>(W2 + (size_t)d * 16);
    float4 q0 = src[0], q1 = src[1], q2 = src[2], q3 = src[3];
    float v[16] = {q0.x, q0.y, q0.z, q0.w, q1.x, q1.y, q1.z, q1.w,
                   q2.x, q2.y, q2.z, q2.w, q3.x, q3.y, q3.z, q3.w};
#pragma unroll
    for (int c = 0; c < 16; ++c) {
      short hh, ll;
      split1(v[c], hh, ll);
      wh[(size_t)c * D + d] = (ushort)hh;
      wl[(size_t)c * D + d] = (ushort)ll;
    }
  } else if (b < 64) {
    int q = (b - 32) * 256 + tid;  // 0..8191 ; covers 16*8192 W1 floats
#pragma unroll
    for (int j = 0; j < 4; ++j) {
      int idx = (q + j * 8192) * 4;
      float4 qv = *reinterpret_cast<const float4*>(W1 + idx);
      short h0, l0, h1, l1, h2, l2, h3, l3;
      split1(qv.x, h0, l0); split1(qv.y, h1, l1);
      split1(qv.z, h2, l2); split1(qv.w, h3, l3);
      ushort4 vh = {(ushort)h0, (ushort)h1, (ushort)h2, (ushort)h3};
      ushort4 vl = {(ushort)l0, (ushort)l1, (ushort)l2, (ushort)l3};
      *reinterpret_cast<ushort4*>(wh + (size_t)16 * D + idx) = vh;
      *reinterpret_cast<ushort4*>(wl + (size_t)16 * D + idx) = vl;
    }
  } else if (b < 80) {
    int t = (b - 64) * 256 + tid;
    float4 z = {0.f, 0.f, 0.f, 0.f};
    float4* dst = reinterpret_cast<float4*>(ac);
#pragma unroll
    for (int j = 0; j < 4; ++j) dst[t + j * 4096] = z;
  } else {
    int bb = b - 80;
    int kc = bb & 7, l = bb >> 3;
    int d = kc * 1024 + tid * 4;
    float4 uv = *reinterpret_cast<const float4*>(u + (size_t)l * D + d);
    float acc[16];
#pragma unroll
    for (int h = 0; h < 16; ++h) {
      float4 wv = *reinterpret_cast<const float4*>(W1 + (size_t)h * D + d);
      float t = fmaf(uv.x, wv.x, 0.f);
      t = fmaf(uv.y, wv.y, t);
      t = fmaf(uv.z, wv.z, t);
      acc[h] = fmaf(uv.w, wv.w, t);
    }
#pragma unroll
    for (int h = 0; h < 16; ++h)
      for (int off = 1; off < 64; off <<= 1) acc[h] += __shfl_xor(acc[h], off);
    __shared__ float red[4][16];
    int lane = tid & 63, wv_ = tid >> 6;
    if (lane == 0) {
#pragma unroll
      for (int h = 0; h < 16; ++h) red[wv_][h] = acc[h];
    }
    __syncthreads();
    if (tid < 16)
      pre[((size_t)l * 8 + kc) * 16 + tid] =
          red[0][tid] + red[1][tid] + red[2][tid] + red[3][tid];
  }
}

// K2: fragment-direct split-bf16 MFMA GEMM with 2-deep software pipeline.
// Grid (KP=32, 32 rowgroups) = 1024 blocks x 4 waves.
// Per kk: prefetch kk+1's 6 loads BEFORE consuming kk -> ~12 loads in flight.
__global__ __launch_bounds__(256) void k_trace_ac(
    const float* __restrict__ w,
    const ushort* __restrict__ wh, const ushort* __restrict__ wl,
    float* __restrict__ ac) {
  int tid = threadIdx.x;
  int wave = tid >> 6, lane = tid & 63;
  int lrow = lane & 15, kg = lane >> 4;
  int kp = blockIdx.x;
  int rt = blockIdx.y * 4 + wave;   // rowtile 0..127
  int m0 = rt * 16;
  int k0 = kp * CHUNK;

  const float*  wrow = w  + (size_t)(m0 + lrow) * D + k0 + kg * 8;
  const ushort* bh0  = wh + (size_t)lrow * D + k0 + kg * 8;
  const ushort* bl0  = wl + (size_t)lrow * D + k0 + kg * 8;
  const ushort* bh1  = bh0 + (size_t)16 * D;
  const ushort* bl1  = bl0 + (size_t)16 * D;

  f32x4 acc0 = {0.f, 0.f, 0.f, 0.f};
  f32x4 acc1 = {0.f, 0.f, 0.f, 0.f};

  // prologue: load kk=0
  float4 a0 = *reinterpret_cast<const float4*>(wrow);
  float4 a1 = *reinterpret_cast<const float4*>(wrow + 4);
  bf16x8 vbh0 = *reinterpret_cast<const bf16x8*>(bh0);
  bf16x8 vbl0 = *reinterpret_cast<const bf16x8*>(bl0);
  bf16x8 vbh1 = *reinterpret_cast<const bf16x8*>(bh1);
  bf16x8 vbl1 = *reinterpret_cast<const bf16x8*>(bl1);

#pragma unroll
  for (int kk = 0; kk < CHUNK / 32; ++kk) {
    // issue next-iteration loads first (hide latency under split+MFMA)
    float4 na0, na1;
    bf16x8 nbh0, nbl0, nbh1, nbl1;
    if (kk + 1 < CHUNK / 32) {
      int noff = (kk + 1) * 32;
      na0  = *reinterpret_cast<const float4*>(wrow + noff);
      na1  = *reinterpret_cast<const float4*>(wrow + noff + 4);
      nbh0 = *reinterpret_cast<const bf16x8*>(bh0 + noff);
      nbl0 = *reinterpret_cast<const bf16x8*>(bl0 + noff);
      nbh1 = *reinterpret_cast<const bf16x8*>(bh1 + noff);
      nbl1 = *reinterpret_cast<const bf16x8*>(bl1 + noff);
    }
    bf16x8 ah, al;
    split8(a0, a1, ah, al);
    acc0 = __builtin_amdgcn_mfma_f32_16x16x32_bf16(ah, vbh0, acc0, 0, 0, 0);
    acc0 = __builtin_amdgcn_mfma_f32_16x16x32_bf16(ah, vbl0, acc0, 0, 0, 0);
    acc0 = __builtin_amdgcn_mfma_f32_16x16x32_bf16(al, vbh0, acc0, 0, 0, 0);
    acc1 = __builtin_amdgcn_mfma_f32_16x16x32_bf16(ah, vbh1, acc1, 0, 0, 0);
    acc1 = __builtin_amdgcn_mfma_f32_16x16x32_bf16(ah, vbl1, acc1, 0, 0, 0);
    acc1 = __builtin_amdgcn_mfma_f32_16x16x32_bf16(al, vbh1, acc1, 0, 0, 0);
    if (kk + 1 < CHUNK / 32) {
      a0 = na0; a1 = na1;
      vbh0 = nbh0; vbl0 = nbl0; vbh1 = nbh1; vbl1 = nbl1;
    }
  }

  // C/D layout: col = lane&15, row = (lane>>4)*4 + reg  [measured m89]
  float* dst = ac + (size_t)(m0 + kg * 4) * 32;
#pragma unroll
  for (int j = 0; j < 4; ++j) {
    atomicAdd(dst + (size_t)j * 32 + lrow,      acc0[j]);
    atomicAdd(dst + (size_t)j * 32 + 16 + lrow, acc1[j]);
  }
}

// K3 (fused tail, role-split by blockIdx.x):
//   [0,128):    f[l][d] = b2[d] + sum_h tanh(pre_l_h) * W2[d][h]
//   [128,384):  8 rows each: trace = sum_h s*a*c, reduce, atomicAdd mean
__global__ __launch_bounds__(256) void k_tail(
    const float* __restrict__ pre, const float* __restrict__ b1,
    const float* __restrict__ W2, const float* __restrict__ b2,
    const float* __restrict__ ac, float* __restrict__ out) {
  __shared__ float hl[8][16];
  __shared__ float s[16];
  __shared__ float red[4];
  int b = blockIdx.x, tid = threadIdx.x;
  if (b >= 128) {
    int bb = b - 128;           // 0..255, 8 rows each
    int l = bb >> 3;
    if (tid < 16) {
      float p = b1[tid];
#pragma unroll
      for (int kc = 0; kc < 8; ++kc) p += pre[((size_t)l * 8 + kc) * 16 + tid];
      float t = tanhf(p);
      s[tid] = 1.f - t * t;
    }
    __syncthreads();
    int c = tid & 31;
    float acc = ac[(size_t)bb * 256 + tid];  // contiguous [8 rows][32]
    float partner = __shfl_xor(acc, 16);
    float t = (c < 16) ? s[c] * acc * partner : 0.f;
#pragma unroll
    for (int off = 1; off < 64; off <<= 1) t += __shfl_xor(t, off);
    int lane = tid & 63, wv_ = tid >> 6;
    if (lane == 0) red[wv_] = t;
    __syncthreads();
    if (tid == 0)
      atomicAdd(out + (size_t)L * D,
                (red[0] + red[1] + red[2] + red[3]) * (1.0f / (float)(L * T)));
    return;
  }
  // f path
  int lg = b >> 5;
  if (tid < 128) {
    int ll = tid >> 4, h = tid & 15, l = lg * 8 + ll;
    float p = b1[h];
#pragma unroll
    for (int kc = 0; kc < 8; ++kc) p += pre[((size_t)l * 8 + kc) * 16 + h];
    hl[ll][h] = tanhf(p);
  }
  __syncthreads();
  int d = (b & 31) * 256 + tid;
  const float4* w2r = reinterpret_cast<const float4*>(W2 + (size_t)d * 16);
  float4 q0 = w2r[0], q1 = w2r[1], q2 = w2r[2], q3 = w2r[3];
  float w2v[16] = {q0.x, q0.y, q0.z, q0.w, q1.x, q1.y, q1.z, q1.w,
                   q2.x, q2.y, q2.z, q2.w, q3.x, q3.y, q3.z, q3.w};
  float bv = b2[d];
#pragma unroll
  for (int ll = 0; ll < 8; ++ll) {
    float fv = bv;
#pragma unroll
    for (int h = 0; h < 16; ++h) fv = fmaf(hl[ll][h], w2v[h], fv);
    out[(size_t)(lg * 8 + ll) * D + d] = fv;
  }
}

extern "C" void kernel_launch(void* const* d_in, const int* in_sizes, int n_in,
                              void* d_out, int out_size, void* d_ws, size_t ws_size,
                              hipStream_t stream) {
  const float* u  = (const float*)d_in[0];
  const float* w  = (const float*)d_in[1];
  const float* W1 = (const float*)d_in[2];
  const float* b1 = (const float*)d_in[3];
  const float* W2 = (const float*)d_in[4];
  const float* b2 = (const float*)d_in[5];
  float* out = (float*)d_out;
  float* ws  = (float*)d_ws;
  ushort* wcat_h = (ushort*)(ws + WS_WH);
  ushort* wcat_l = (ushort*)(ws + WS_WL);
  float* pre = ws + WS_PRE;
  float* acb = ws + WS_AC;

  hipLaunchKernelGGL(k_setup,    dim3(336), dim3(256), 0, stream,
                     u, W1, W2, wcat_h, wcat_l, pre, acb, out);
  hipLaunchKernelGGL(k_trace_ac, dim3(KP, 32), dim3(256), 0, stream,
                     w, wcat_h, wcat_l, acb);
  hipLaunchKernelGGL(k_tail,     dim3(384), dim3(256), 0, stream,
                     pre, b1, W2, b2, acb, out);
}